// Round 8
// baseline (101.747 us; speedup 1.0000x reference)
//
#include <hip/hip_runtime.h>
#include <hip/hip_bf16.h>

// Problem constants
#define BATCH   4096
#define TWO_B   8192
#define DIM     128
#define INV_TEMP 2.0f      // 1/TEMP, TEMP=0.5
// sqrt(INV_TEMP * log2(e)) folded into the stored bf16 vectors, so the
// similarity accumulator comes out as sim * INV_TEMP * log2(e) and the
// epilogue is a bare exp2.
#define SFOLD 1.6986436f   // sqrt(2.8853900817779268)

typedef __attribute__((ext_vector_type(8))) short bf16x8;   // 8 bf16 = 4 VGPRs
typedef __attribute__((ext_vector_type(4))) float f32x4;

#define CS 32   // column splits: each wave covers 64 rows x 256 cols
#define ROWS_PER_BLOCK 256
#define TILES_PER_WAVE 4   // 4 x 64-col tiles = 256 cols

// Workspace layout (bytes):
//   zb     : __hip_bfloat16[TWO_B*DIM]  [0, 2097152)   pre-scaled by SFOLD
//   rowsum : float[TWO_B]               zeroed by k_normalize
//   ps     : float[1024]                per-block possum partials
#define ZB_BYTES   (TWO_B * DIM * 2)
#define RS_OFFSET  ZB_BYTES
#define PS_OFFSET  (RS_OFFSET + TWO_B * 4)

// ---------------------------------------------------------------------------
// Kernel 1: L2-normalize rows of zi AND zj (paired), write bf16 z rows scaled
// by SFOLD, write per-block possum partial, and zero rowsum (8 floats/block).
// ---------------------------------------------------------------------------
__global__ __launch_bounds__(256) void k_normalize(const float* __restrict__ zi,
                                                   const float* __restrict__ zj,
                                                   __hip_bfloat16* __restrict__ zb,
                                                   float* __restrict__ ps,
                                                   float* __restrict__ rowsum) {
    int w = threadIdx.x >> 6;
    int lane = threadIdx.x & 63;
    int r = blockIdx.x * 4 + w;                       // [0, BATCH)

    // zero rowsum: 1024 blocks x 8 floats = 8192
    if (threadIdx.x < 8) rowsum[blockIdx.x * 8 + threadIdx.x] = 0.0f;

    float2 vi = *reinterpret_cast<const float2*>(zi + (size_t)r * DIM + lane * 2);
    float2 vj = *reinterpret_cast<const float2*>(zj + (size_t)r * DIM + lane * 2);
    float ssi = vi.x * vi.x + vi.y * vi.y;
    float ssj = vj.x * vj.x + vj.y * vj.y;
    #pragma unroll
    for (int m = 1; m < 64; m <<= 1) {
        ssi += __shfl_xor(ssi, m, 64);
        ssj += __shfl_xor(ssj, m, 64);
    }
    float invi = 1.0f / fmaxf(sqrtf(ssi), 1e-12f);
    float invj = 1.0f / fmaxf(sqrtf(ssj), 1e-12f);

    float nix = vi.x * invi, niy = vi.y * invi;
    float njx = vj.x * invj, njy = vj.y * invj;

    __hip_bfloat162 hi2, hj2;
    hi2.x = __float2bfloat16(nix * SFOLD);
    hi2.y = __float2bfloat16(niy * SFOLD);
    hj2.x = __float2bfloat16(njx * SFOLD);
    hj2.y = __float2bfloat16(njy * SFOLD);
    *reinterpret_cast<__hip_bfloat162*>(zb + (size_t)r * DIM + lane * 2) = hi2;
    *reinterpret_cast<__hip_bfloat162*>(zb + (size_t)(r + BATCH) * DIM + lane * 2) = hj2;

    // paired-diagonal dot in fp32 (unscaled)
    float d = nix * njx + niy * njy;
    #pragma unroll
    for (int m = 1; m < 64; m <<= 1) d += __shfl_xor(d, m, 64);

    __shared__ float red[4];
    if (lane == 0) red[w] = d;
    __syncthreads();
    if (threadIdx.x == 0)
        ps[blockIdx.x] = red[0] + red[1] + red[2] + red[3];
}

// ---------------------------------------------------------------------------
// Kernel 2: similarity + fused exp2/row-sum. NO LDS, NO barriers.
// Grid: (TWO_B/256) * CS = 1024 blocks, 256 threads (4 waves) ->
// 4 blocks/CU, 4 waves/SIMD (TLP hides global-load latency).
// Wave w owns rows [rowBlock*256 + w*64, +64); all 4 waves share cols
// [split*256, +256) (4 x 64-col tiles) so B reads hit L1 after wave 0.
// A-fragments live in registers for the whole kernel (16 x bf16x8).
// MFMA C/D layout (m89): col = lane&15, row = (lane>>4)*4 + reg.
// ---------------------------------------------------------------------------
__global__ __launch_bounds__(256, 4) void k_sim(const __hip_bfloat16* __restrict__ zb,
                                                float* __restrict__ rowsum) {
    const int t = threadIdx.x;
    const int w = t >> 6;
    const int lane = t & 63;
    const int lo = lane & 15, hi = lane >> 4;

    const int rowBlock = blockIdx.x / CS;
    const int split    = blockIdx.x % CS;
    const int rowBase  = rowBlock * ROWS_PER_BLOCK + w * 64;

    const char* zbB = reinterpret_cast<const char*>(zb);

    // A fragments: a[i][ks] = 16B at row (rowBase+i*16+lo), k-chunk (ks*4+hi)
    bf16x8 a[4][4];
    #pragma unroll
    for (int i = 0; i < 4; ++i) {
        const char* rp = zbB + (size_t)(rowBase + i * 16 + lo) * 256 + hi * 16;
        #pragma unroll
        for (int ks = 0; ks < 4; ++ks)
            a[i][ks] = *reinterpret_cast<const bf16x8*>(rp + ks * 64);
    }

    float psum[4][4];
    #pragma unroll
    for (int i = 0; i < 4; ++i)
        #pragma unroll
        for (int p = 0; p < 4; ++p) psum[i][p] = 0.0f;

    for (int ct = 0; ct < TILES_PER_WAVE; ++ct) {
        const int colBase = split * 256 + ct * 64;

        // B fragments for this 64-col tile (straight from global; L1-resident
        // for waves 1..3 of the block).
        bf16x8 b[4][4];
        #pragma unroll
        for (int j = 0; j < 4; ++j) {
            const char* rp = zbB + (size_t)(colBase + j * 16 + lo) * 256 + hi * 16;
            #pragma unroll
            for (int ks = 0; ks < 4; ++ks)
                b[j][ks] = *reinterpret_cast<const bf16x8*>(rp + ks * 64);
        }

        f32x4 acc[4][4];
        #pragma unroll
        for (int i = 0; i < 4; ++i)
            #pragma unroll
            for (int j = 0; j < 4; ++j) acc[i][j] = (f32x4){0.f, 0.f, 0.f, 0.f};

        #pragma unroll
        for (int ks = 0; ks < 4; ++ks)
            #pragma unroll
            for (int i = 0; i < 4; ++i)
                #pragma unroll
                for (int j = 0; j < 4; ++j)
                    acc[i][j] = __builtin_amdgcn_mfma_f32_16x16x32_bf16(
                        a[i][ks], b[j][ks], acc[i][j], 0, 0, 0);

        // epilogue: acc already = sim * INV_TEMP * log2(e)  ->  exp2 and sum.
        if (colBase == rowBase) {
            // diagonal tile: element (i,j,p) is the self-sim when j==i and
            // lo == hi*4+p  (gr == gc); exclude it.
            #pragma unroll
            for (int i = 0; i < 4; ++i)
                #pragma unroll
                for (int p = 0; p < 4; ++p) {
                    float s = 0.0f;
                    #pragma unroll
                    for (int j = 0; j < 4; ++j) {
                        float e = exp2f(acc[i][j][p]);
                        if (j == i && lo == hi * 4 + p) e = 0.0f;
                        s += e;
                    }
                    psum[i][p] += s;
                }
        } else {
            #pragma unroll
            for (int i = 0; i < 4; ++i)
                #pragma unroll
                for (int p = 0; p < 4; ++p) {
                    float s = 0.0f;
                    #pragma unroll
                    for (int j = 0; j < 4; ++j) s += exp2f(acc[i][j][p]);
                    psum[i][p] += s;
                }
        }
    }

    // reduce over the 16 lo-lanes (distinct columns) and atomicAdd per row.
    #pragma unroll
    for (int i = 0; i < 4; ++i) {
        #pragma unroll
        for (int p = 0; p < 4; ++p) {
            float s = psum[i][p];
            s += __shfl_xor(s, 1, 64);
            s += __shfl_xor(s, 2, 64);
            s += __shfl_xor(s, 4, 64);
            s += __shfl_xor(s, 8, 64);
            if (lo == 0)
                atomicAdd(&rowsum[rowBase + i * 16 + hi * 4 + p], s);
        }
    }
}

// ---------------------------------------------------------------------------
// Kernel 3: loss = (sum_r log(rowsum[r]) - 2*INV_TEMP*possum) / TWO_B
// ---------------------------------------------------------------------------
__global__ __launch_bounds__(1024) void k_final(const float* __restrict__ rowsum,
                                                const float* __restrict__ ps,
                                                float* __restrict__ out) {
    __shared__ float redl[1024];
    __shared__ float redp[1024];
    const int t = threadIdx.x;

    float s = 0.0f;
    #pragma unroll
    for (int q = 0; q < TWO_B / 1024; ++q) s += logf(rowsum[t + q * 1024]);
    float p = ps[t];

    redl[t] = s;
    redp[t] = p;
    __syncthreads();
    #pragma unroll
    for (int off = 512; off > 0; off >>= 1) {
        if (t < off) {
            redl[t] += redl[t + off];
            redp[t] += redp[t + off];
        }
        __syncthreads();
    }
    if (t == 0)
        out[0] = (redl[0] - 2.0f * INV_TEMP * redp[0]) / (float)TWO_B;
}

// ---------------------------------------------------------------------------
extern "C" void kernel_launch(void* const* d_in, const int* in_sizes, int n_in,
                              void* d_out, int out_size, void* d_ws, size_t ws_size,
                              hipStream_t stream) {
    const float* zi = (const float*)d_in[0];
    const float* zj = (const float*)d_in[1];
    float* out = (float*)d_out;

    char* ws = (char*)d_ws;
    __hip_bfloat16* zb = (__hip_bfloat16*)ws;
    float* rowsum = (float*)(ws + RS_OFFSET);
    float* ps = (float*)(ws + PS_OFFSET);

    k_normalize<<<BATCH / 4, 256, 0, stream>>>(zi, zj, zb, ps, rowsum);
    k_sim<<<(TWO_B / ROWS_PER_BLOCK) * CS, 256, 0, stream>>>(zb, rowsum);
    k_final<<<1, 1024, 0, stream>>>(rowsum, ps, out);
}

// Round 9
// 59.044 us; speedup vs baseline: 1.7232x; 1.7232x over previous
//
#include <hip/hip_runtime.h>
#include <hip/hip_bf16.h>

// Problem constants
#define BATCH   4096
#define TWO_B   8192
#define DIM     128
#define INV_TEMP 2.0f      // 1/TEMP, TEMP=0.5
// sqrt(INV_TEMP * log2(e)) folded into the stored bf16 vectors, so the
// similarity accumulator comes out as sim * INV_TEMP * log2(e) and the
// epilogue is a bare exp2.
#define SFOLD 1.6986436f   // sqrt(2.8853900817779268)

typedef __attribute__((ext_vector_type(8))) short bf16x8;   // 8 bf16 = 4 VGPRs
typedef __attribute__((ext_vector_type(4))) float f32x4;

#define CS 32   // column splits: each wave covers 64 rows x 256 cols
#define ROWS_PER_BLOCK 256
#define TILES_PER_WAVE 4   // 4 x 64-col tiles = 256 cols

// Workspace layout (bytes):
//   zb     : __hip_bfloat16[TWO_B*DIM]  [0, 2097152)   pre-scaled by SFOLD
//   rowsum : float[TWO_B]               zeroed by k_normalize
//   ps     : float[1024]                per-block possum partials
#define ZB_BYTES   (TWO_B * DIM * 2)
#define RS_OFFSET  ZB_BYTES
#define PS_OFFSET  (RS_OFFSET + TWO_B * 4)

// ---------------------------------------------------------------------------
// Kernel 1: L2-normalize rows of zi AND zj (paired), write bf16 z rows scaled
// by SFOLD, write per-block possum partial, and zero rowsum (8 floats/block).
// ---------------------------------------------------------------------------
__global__ __launch_bounds__(256) void k_normalize(const float* __restrict__ zi,
                                                   const float* __restrict__ zj,
                                                   __hip_bfloat16* __restrict__ zb,
                                                   float* __restrict__ ps,
                                                   float* __restrict__ rowsum) {
    int w = threadIdx.x >> 6;
    int lane = threadIdx.x & 63;
    int r = blockIdx.x * 4 + w;                       // [0, BATCH)

    // zero rowsum: 1024 blocks x 8 floats = 8192
    if (threadIdx.x < 8) rowsum[blockIdx.x * 8 + threadIdx.x] = 0.0f;

    float2 vi = *reinterpret_cast<const float2*>(zi + (size_t)r * DIM + lane * 2);
    float2 vj = *reinterpret_cast<const float2*>(zj + (size_t)r * DIM + lane * 2);
    float ssi = vi.x * vi.x + vi.y * vi.y;
    float ssj = vj.x * vj.x + vj.y * vj.y;
    #pragma unroll
    for (int m = 1; m < 64; m <<= 1) {
        ssi += __shfl_xor(ssi, m, 64);
        ssj += __shfl_xor(ssj, m, 64);
    }
    float invi = 1.0f / fmaxf(sqrtf(ssi), 1e-12f);
    float invj = 1.0f / fmaxf(sqrtf(ssj), 1e-12f);

    float nix = vi.x * invi, niy = vi.y * invi;
    float njx = vj.x * invj, njy = vj.y * invj;

    __hip_bfloat162 hi2, hj2;
    hi2.x = __float2bfloat16(nix * SFOLD);
    hi2.y = __float2bfloat16(niy * SFOLD);
    hj2.x = __float2bfloat16(njx * SFOLD);
    hj2.y = __float2bfloat16(njy * SFOLD);
    *reinterpret_cast<__hip_bfloat162*>(zb + (size_t)r * DIM + lane * 2) = hi2;
    *reinterpret_cast<__hip_bfloat162*>(zb + (size_t)(r + BATCH) * DIM + lane * 2) = hj2;

    // paired-diagonal dot in fp32 (unscaled)
    float d = nix * njx + niy * njy;
    #pragma unroll
    for (int m = 1; m < 64; m <<= 1) d += __shfl_xor(d, m, 64);

    __shared__ float red[4];
    if (lane == 0) red[w] = d;
    __syncthreads();
    if (threadIdx.x == 0)
        ps[blockIdx.x] = red[0] + red[1] + red[2] + red[3];
}

// ---------------------------------------------------------------------------
// Kernel 2: similarity + fused exp2/row-sum. NO LDS, NO barriers.
// Grid: (TWO_B/256) * CS = 1024 blocks, 256 threads (4 waves) ->
// 4 blocks/CU, 4 waves/SIMD (TLP hides global-load latency).
// launch_bounds(256,2): natural VGPR ~100 (<=128), NO spill — the (256,4)
// variant forced VGPR=64 and spilled ~150 MB/dispatch to scratch (round 8).
// Wave w owns rows [rowBlock*256 + w*64, +64); all 4 waves share cols
// [split*256, +256) (4 x 64-col tiles) so B reads hit L1 after wave 0.
// A-fragments live in registers for the whole kernel (16 x bf16x8).
// MFMA C/D layout (m89): col = lane&15, row = (lane>>4)*4 + reg.
// ---------------------------------------------------------------------------
__global__ __launch_bounds__(256, 2) void k_sim(const __hip_bfloat16* __restrict__ zb,
                                                float* __restrict__ rowsum) {
    const int t = threadIdx.x;
    const int w = t >> 6;
    const int lane = t & 63;
    const int lo = lane & 15, hi = lane >> 4;

    const int rowBlock = blockIdx.x / CS;
    const int split    = blockIdx.x % CS;
    const int rowBase  = rowBlock * ROWS_PER_BLOCK + w * 64;

    const char* zbB = reinterpret_cast<const char*>(zb);

    // A fragments: a[i][ks] = 16B at row (rowBase+i*16+lo), k-chunk (ks*4+hi)
    bf16x8 a[4][4];
    #pragma unroll
    for (int i = 0; i < 4; ++i) {
        const char* rp = zbB + (size_t)(rowBase + i * 16 + lo) * 256 + hi * 16;
        #pragma unroll
        for (int ks = 0; ks < 4; ++ks)
            a[i][ks] = *reinterpret_cast<const bf16x8*>(rp + ks * 64);
    }

    float psum[4][4];
    #pragma unroll
    for (int i = 0; i < 4; ++i)
        #pragma unroll
        for (int p = 0; p < 4; ++p) psum[i][p] = 0.0f;

    for (int ct = 0; ct < TILES_PER_WAVE; ++ct) {
        const int colBase = split * 256 + ct * 64;

        // B fragments for this 64-col tile (straight from global; L1-resident
        // for waves 1..3 of the block).
        bf16x8 b[4][4];
        #pragma unroll
        for (int j = 0; j < 4; ++j) {
            const char* rp = zbB + (size_t)(colBase + j * 16 + lo) * 256 + hi * 16;
            #pragma unroll
            for (int ks = 0; ks < 4; ++ks)
                b[j][ks] = *reinterpret_cast<const bf16x8*>(rp + ks * 64);
        }

        f32x4 acc[4][4];
        #pragma unroll
        for (int i = 0; i < 4; ++i)
            #pragma unroll
            for (int j = 0; j < 4; ++j) acc[i][j] = (f32x4){0.f, 0.f, 0.f, 0.f};

        #pragma unroll
        for (int ks = 0; ks < 4; ++ks)
            #pragma unroll
            for (int i = 0; i < 4; ++i)
                #pragma unroll
                for (int j = 0; j < 4; ++j)
                    acc[i][j] = __builtin_amdgcn_mfma_f32_16x16x32_bf16(
                        a[i][ks], b[j][ks], acc[i][j], 0, 0, 0);

        // epilogue: acc already = sim * INV_TEMP * log2(e)  ->  exp2 and sum.
        if (colBase == rowBase) {
            // diagonal tile: element (i,j,p) is the self-sim when j==i and
            // lo == hi*4+p  (gr == gc); exclude it.
            #pragma unroll
            for (int i = 0; i < 4; ++i)
                #pragma unroll
                for (int p = 0; p < 4; ++p) {
                    float s = 0.0f;
                    #pragma unroll
                    for (int j = 0; j < 4; ++j) {
                        float e = exp2f(acc[i][j][p]);
                        if (j == i && lo == hi * 4 + p) e = 0.0f;
                        s += e;
                    }
                    psum[i][p] += s;
                }
        } else {
            #pragma unroll
            for (int i = 0; i < 4; ++i)
                #pragma unroll
                for (int p = 0; p < 4; ++p) {
                    float s = 0.0f;
                    #pragma unroll
                    for (int j = 0; j < 4; ++j) s += exp2f(acc[i][j][p]);
                    psum[i][p] += s;
                }
        }
    }

    // reduce over the 16 lo-lanes (distinct columns) and atomicAdd per row.
    #pragma unroll
    for (int i = 0; i < 4; ++i) {
        #pragma unroll
        for (int p = 0; p < 4; ++p) {
            float s = psum[i][p];
            s += __shfl_xor(s, 1, 64);
            s += __shfl_xor(s, 2, 64);
            s += __shfl_xor(s, 4, 64);
            s += __shfl_xor(s, 8, 64);
            if (lo == 0)
                atomicAdd(&rowsum[rowBase + i * 16 + hi * 4 + p], s);
        }
    }
}

// ---------------------------------------------------------------------------
// Kernel 3: loss = (sum_r log(rowsum[r]) - 2*INV_TEMP*possum) / TWO_B
// ---------------------------------------------------------------------------
__global__ __launch_bounds__(1024) void k_final(const float* __restrict__ rowsum,
                                                const float* __restrict__ ps,
                                                float* __restrict__ out) {
    __shared__ float redl[1024];
    __shared__ float redp[1024];
    const int t = threadIdx.x;

    float s = 0.0f;
    #pragma unroll
    for (int q = 0; q < TWO_B / 1024; ++q) s += logf(rowsum[t + q * 1024]);
    float p = ps[t];

    redl[t] = s;
    redp[t] = p;
    __syncthreads();
    #pragma unroll
    for (int off = 512; off > 0; off >>= 1) {
        if (t < off) {
            redl[t] += redl[t + off];
            redp[t] += redp[t + off];
        }
        __syncthreads();
    }
    if (t == 0)
        out[0] = (redl[0] - 2.0f * INV_TEMP * redp[0]) / (float)TWO_B;
}

// ---------------------------------------------------------------------------
extern "C" void kernel_launch(void* const* d_in, const int* in_sizes, int n_in,
                              void* d_out, int out_size, void* d_ws, size_t ws_size,
                              hipStream_t stream) {
    const float* zi = (const float*)d_in[0];
    const float* zj = (const float*)d_in[1];
    float* out = (float*)d_out;

    char* ws = (char*)d_ws;
    __hip_bfloat16* zb = (__hip_bfloat16*)ws;
    float* rowsum = (float*)(ws + RS_OFFSET);
    float* ps = (float*)(ws + PS_OFFSET);

    k_normalize<<<BATCH / 4, 256, 0, stream>>>(zi, zj, zb, ps, rowsum);
    k_sim<<<(TWO_B / ROWS_PER_BLOCK) * CS, 256, 0, stream>>>(zb, rowsum);
    k_final<<<1, 1024, 0, stream>>>(rowsum, ps, out);
}

// Round 10
// 55.358 us; speedup vs baseline: 1.8380x; 1.0666x over previous
//
#include <hip/hip_runtime.h>
#include <hip/hip_bf16.h>

// Problem constants
#define BATCH   4096
#define TWO_B   8192
#define DIM     128
#define INV_TEMP 2.0f      // 1/TEMP, TEMP=0.5
// sqrt(INV_TEMP * log2(e)) folded into the stored bf16 vectors, so the
// similarity accumulator comes out as sim * INV_TEMP * log2(e) and the
// epilogue is a bare exp2.
#define SFOLD 1.6986436f   // sqrt(2.8853900817779268)

typedef __attribute__((ext_vector_type(8))) short bf16x8;   // 8 bf16 = 4 VGPRs
typedef __attribute__((ext_vector_type(4))) float f32x4;

#define NTB 32             // 8192 / 256 row/col tiles
#define NPAIRS (NTB * (NTB + 1) / 2)   // 528 upper-triangle tile pairs

// Workspace layout (bytes):
//   zb     : __hip_bfloat16[TWO_B*DIM]  [0, 2097152)   pre-scaled by SFOLD
//   rowsum : float[TWO_B]               zeroed by k_normalize
//   ps     : float[1024]                per-block possum partials
#define ZB_BYTES   (TWO_B * DIM * 2)
#define RS_OFFSET  ZB_BYTES
#define PS_OFFSET  (RS_OFFSET + TWO_B * 4)

// ---------------------------------------------------------------------------
// Kernel 1: L2-normalize rows of zi AND zj (paired), write bf16 z rows scaled
// by SFOLD, write per-block possum partial, and zero rowsum (8 floats/block).
// ---------------------------------------------------------------------------
__global__ __launch_bounds__(256) void k_normalize(const float* __restrict__ zi,
                                                   const float* __restrict__ zj,
                                                   __hip_bfloat16* __restrict__ zb,
                                                   float* __restrict__ ps,
                                                   float* __restrict__ rowsum) {
    int w = threadIdx.x >> 6;
    int lane = threadIdx.x & 63;
    int r = blockIdx.x * 4 + w;                       // [0, BATCH)

    // zero rowsum: 1024 blocks x 8 floats = 8192
    if (threadIdx.x < 8) rowsum[blockIdx.x * 8 + threadIdx.x] = 0.0f;

    float2 vi = *reinterpret_cast<const float2*>(zi + (size_t)r * DIM + lane * 2);
    float2 vj = *reinterpret_cast<const float2*>(zj + (size_t)r * DIM + lane * 2);
    float ssi = vi.x * vi.x + vi.y * vi.y;
    float ssj = vj.x * vj.x + vj.y * vj.y;
    #pragma unroll
    for (int m = 1; m < 64; m <<= 1) {
        ssi += __shfl_xor(ssi, m, 64);
        ssj += __shfl_xor(ssj, m, 64);
    }
    float invi = 1.0f / fmaxf(sqrtf(ssi), 1e-12f);
    float invj = 1.0f / fmaxf(sqrtf(ssj), 1e-12f);

    float nix = vi.x * invi, niy = vi.y * invi;
    float njx = vj.x * invj, njy = vj.y * invj;

    __hip_bfloat162 hi2, hj2;
    hi2.x = __float2bfloat16(nix * SFOLD);
    hi2.y = __float2bfloat16(niy * SFOLD);
    hj2.x = __float2bfloat16(njx * SFOLD);
    hj2.y = __float2bfloat16(njy * SFOLD);
    *reinterpret_cast<__hip_bfloat162*>(zb + (size_t)r * DIM + lane * 2) = hi2;
    *reinterpret_cast<__hip_bfloat162*>(zb + (size_t)(r + BATCH) * DIM + lane * 2) = hj2;

    // paired-diagonal dot in fp32 (unscaled)
    float d = nix * njx + niy * njy;
    #pragma unroll
    for (int m = 1; m < 64; m <<= 1) d += __shfl_xor(d, m, 64);

    __shared__ float red[4];
    if (lane == 0) red[w] = d;
    __syncthreads();
    if (threadIdx.x == 0)
        ps[blockIdx.x] = red[0] + red[1] + red[2] + red[3];
}

// ---------------------------------------------------------------------------
// Kernel 2: SYMMETRIC similarity + fused exp2/row-sum. S[r,c]=S[c,r], so only
// upper-triangle 256x256 tile-pairs (rb<=cb) are computed; strict-upper tiles
// add each exp to BOTH rowsum[row] (register psum + atomic) and rowsum[col]
// (LDS colacc + one atomic per col per block). Diagonal blocks (rb==cb)
// compute their full square with the self-mask, rows only.
// Grid: NPAIRS*2 = 1056 blocks (cs = which 128-col half), 256 threads
// (4 waves, each 64 rows x 128 cols in 2 x 64-col tiles). No A/B LDS.
// launch_bounds(256,2): natural VGPR ~100, no spill (round-8 lesson: (256,4)
// forced VGPR=64 and spilled ~150 MB/dispatch).
// MFMA C/D layout (m89): col = lane&15, row = (lane>>4)*4 + reg.
// ---------------------------------------------------------------------------
__global__ __launch_bounds__(256, 2) void k_sim(const __hip_bfloat16* __restrict__ zb,
                                                float* __restrict__ rowsum) {
    __shared__ float colacc[128];

    const int t = threadIdx.x;
    const int w = t >> 6;
    const int lane = t & 63;
    const int lo = lane & 15, hi = lane >> 4;

    // block -> (rb, cb, cs)
    const int pair = blockIdx.x >> 1;
    const int cs   = blockIdx.x & 1;
    int rb = 0, accum = 0;
    while (accum + (NTB - rb) <= pair) { accum += NTB - rb; ++rb; }
    const int cb = rb + (pair - accum);
    const bool offdiag = (rb != cb);

    const int rowBase = rb * 256 + w * 64;
    const int colWin  = cb * 256 + cs * 128;

    if (t < 128) colacc[t] = 0.0f;
    __syncthreads();

    const char* zbB = reinterpret_cast<const char*>(zb);

    // A fragments: a[i][ks] = 16B at row (rowBase+i*16+lo), k-chunk (ks*4+hi)
    bf16x8 a[4][4];
    #pragma unroll
    for (int i = 0; i < 4; ++i) {
        const char* rp = zbB + (size_t)(rowBase + i * 16 + lo) * 256 + hi * 16;
        #pragma unroll
        for (int ks = 0; ks < 4; ++ks)
            a[i][ks] = *reinterpret_cast<const bf16x8*>(rp + ks * 64);
    }

    float psum[4][4];
    #pragma unroll
    for (int i = 0; i < 4; ++i)
        #pragma unroll
        for (int p = 0; p < 4; ++p) psum[i][p] = 0.0f;

    #pragma unroll
    for (int ct = 0; ct < 2; ++ct) {
        const int colBase = colWin + ct * 64;

        bf16x8 b[4][4];
        #pragma unroll
        for (int j = 0; j < 4; ++j) {
            const char* rp = zbB + (size_t)(colBase + j * 16 + lo) * 256 + hi * 16;
            #pragma unroll
            for (int ks = 0; ks < 4; ++ks)
                b[j][ks] = *reinterpret_cast<const bf16x8*>(rp + ks * 64);
        }

        f32x4 acc[4][4];
        #pragma unroll
        for (int i = 0; i < 4; ++i)
            #pragma unroll
            for (int j = 0; j < 4; ++j) acc[i][j] = (f32x4){0.f, 0.f, 0.f, 0.f};

        #pragma unroll
        for (int ks = 0; ks < 4; ++ks)
            #pragma unroll
            for (int i = 0; i < 4; ++i)
                #pragma unroll
                for (int j = 0; j < 4; ++j)
                    acc[i][j] = __builtin_amdgcn_mfma_f32_16x16x32_bf16(
                        a[i][ks], b[j][ks], acc[i][j], 0, 0, 0);

        // epilogue: acc already = sim * INV_TEMP * log2(e) -> exp2, mask, sum.
        float cps[4] = {0.f, 0.f, 0.f, 0.f};   // per-j col partials (this tile)
        const bool diagTile = (colBase == rowBase);   // only inside diag blocks
        #pragma unroll
        for (int i = 0; i < 4; ++i) {
            #pragma unroll
            for (int p = 0; p < 4; ++p) {
                float s = 0.0f;
                #pragma unroll
                for (int j = 0; j < 4; ++j) {
                    float e = exp2f(acc[i][j][p]);
                    if (diagTile && j == i && lo == hi * 4 + p) e = 0.0f;
                    s += e;
                    cps[j] += e;
                }
                psum[i][p] += s;
            }
        }

        // col-side: reduce cps over the 4 hi-groups (rows) and stash in LDS.
        if (offdiag) {
            #pragma unroll
            for (int j = 0; j < 4; ++j) {
                float v = cps[j];
                v += __shfl_xor(v, 16, 64);
                v += __shfl_xor(v, 32, 64);
                if (hi == 0)
                    atomicAdd(&colacc[ct * 64 + j * 16 + lo], v);
            }
        }
    }

    // row-side: reduce over the 16 lo-lanes (distinct columns), atomic per row.
    #pragma unroll
    for (int i = 0; i < 4; ++i) {
        #pragma unroll
        for (int p = 0; p < 4; ++p) {
            float s = psum[i][p];
            s += __shfl_xor(s, 1, 64);
            s += __shfl_xor(s, 2, 64);
            s += __shfl_xor(s, 4, 64);
            s += __shfl_xor(s, 8, 64);
            if (lo == 0)
                atomicAdd(&rowsum[rowBase + i * 16 + hi * 4 + p], s);
        }
    }

    // flush col partials: one atomic per col per block.
    if (offdiag) {
        __syncthreads();
        if (t < 128) atomicAdd(&rowsum[colWin + t], colacc[t]);
    }
}

// ---------------------------------------------------------------------------
// Kernel 3: loss = (sum_r log(rowsum[r]) - 2*INV_TEMP*possum) / TWO_B
// ---------------------------------------------------------------------------
__global__ __launch_bounds__(1024) void k_final(const float* __restrict__ rowsum,
                                                const float* __restrict__ ps,
                                                float* __restrict__ out) {
    __shared__ float redl[1024];
    __shared__ float redp[1024];
    const int t = threadIdx.x;

    float s = 0.0f;
    #pragma unroll
    for (int q = 0; q < TWO_B / 1024; ++q) s += logf(rowsum[t + q * 1024]);
    float p = ps[t];

    redl[t] = s;
    redp[t] = p;
    __syncthreads();
    #pragma unroll
    for (int off = 512; off > 0; off >>= 1) {
        if (t < off) {
            redl[t] += redl[t + off];
            redp[t] += redp[t + off];
        }
        __syncthreads();
    }
    if (t == 0)
        out[0] = (redl[0] - 2.0f * INV_TEMP * redp[0]) / (float)TWO_B;
}

// ---------------------------------------------------------------------------
extern "C" void kernel_launch(void* const* d_in, const int* in_sizes, int n_in,
                              void* d_out, int out_size, void* d_ws, size_t ws_size,
                              hipStream_t stream) {
    const float* zi = (const float*)d_in[0];
    const float* zj = (const float*)d_in[1];
    float* out = (float*)d_out;

    char* ws = (char*)d_ws;
    __hip_bfloat16* zb = (__hip_bfloat16*)ws;
    float* rowsum = (float*)(ws + RS_OFFSET);
    float* ps = (float*)(ws + PS_OFFSET);

    k_normalize<<<BATCH / 4, 256, 0, stream>>>(zi, zj, zb, ps, rowsum);
    k_sim<<<NPAIRS * 2, 256, 0, stream>>>(zb, rowsum);
    k_final<<<1, 1024, 0, stream>>>(rowsum, ps, out);
}